// Round 12
// baseline (692.926 us; speedup 1.0000x reference)
//
#include <hip/hip_runtime.h>
#include <hip/hip_bf16.h>
#include <cstdint>
#include <cstddef>

#define NN 16000
#define MPAD 16128
#define EE 256000
#define ETOT (EE + NN)
#define RREL 8
#define NHEAD 8
#define DOUT 64
#define HD 512
#define NEG 0.2f

typedef unsigned int u32;
typedef short bf16x8 __attribute__((ext_vector_type(8)));
typedef float f32x4 __attribute__((ext_vector_type(4)));

// ---------- helpers ----------
__device__ inline unsigned short f2bf(float f) {
  u32 i = __float_as_uint(f);
  u32 r = (i + 0x7fff + ((i >> 16) & 1)) >> 16;  // RNE, finite values
  return (unsigned short)r;
}
__device__ inline float bf2f(unsigned short h) {
  return __uint_as_float((u32)h << 16);
}
__device__ inline void g2lds16(const void* g, void* lds) {
  __builtin_amdgcn_global_load_lds(
      (const __attribute__((address_space(1))) unsigned int*)g,
      (__attribute__((address_space(3))) unsigned int*)lds, 16, 0, 0);
}

// ---------- preprocessing ----------
__global__ void k_hist(const int* __restrict__ ei, const int* __restrict__ et,
                       int* __restrict__ deg, int* __restrict__ meta) {
  int e = blockIdx.x * 256 + threadIdx.x;
  if (e >= ETOT) return;
  int dst;
  if (e < EE) { dst = ei[EE + e]; atomicMax(&meta[0], et[e]); }
  else dst = e - EE;
  atomicAdd(&deg[dst], 1);
}

// 16 elems/thread serial prefix + single 1024-wide block scan
__global__ __launch_bounds__(1024) void k_scan(const int* __restrict__ deg,
                                               int* __restrict__ rowptr,
                                               int* __restrict__ fill) {
  __shared__ int sm[1024];
  const int tid = threadIdx.x;
  const int base = tid * 16;
  int local[16];
  int s = 0;
#pragma unroll
  for (int i = 0; i < 16; ++i) {
    int idx = base + i;
    int v = (idx < NN) ? deg[idx] : 0;
    local[i] = s;
    s += v;
  }
  sm[tid] = s;
  __syncthreads();
  for (int off = 1; off < 1024; off <<= 1) {
    int t = (tid >= off) ? sm[tid - off] : 0;
    __syncthreads();
    sm[tid] += t;
    __syncthreads();
  }
  const int pre = (tid > 0) ? sm[tid - 1] : 0;
#pragma unroll
  for (int i = 0; i < 16; ++i) {
    int idx = base + i;
    if (idx < NN) { rowptr[idx] = pre + local[i]; fill[idx] = pre + local[i]; }
  }
  if (tid == 1023) rowptr[NN] = sm[1023];
}

__global__ void k_scatter(const int* __restrict__ ei, const int* __restrict__ et,
                          const float* __restrict__ ea, const int* __restrict__ meta,
                          int* __restrict__ fill, int* __restrict__ csr_src,
                          int* __restrict__ csr_et, float* __restrict__ csr_ea) {
  int e = blockIdx.x * 256 + threadIdx.x;
  if (e >= ETOT) return;
  int src, dst, r; float a;
  if (e < EE) { src = ei[e]; dst = ei[EE + e]; r = et[e]; a = ea[e]; }
  else { src = dst = e - EE; r = (meta[0] + 1) & (RREL - 1); a = 0.5f; }
  int pos = atomicAdd(&fill[dst], 1);
  csr_src[pos] = src; csr_et[pos] = r; csr_ea[pos] = a;
}

// ---------- per-layer small precomputes ----------
// WQK[f, r*16 + j]; extra last block computes cvec
__global__ void k_wqk(const float* __restrict__ W, const float* __restrict__ q,
                      const float* __restrict__ k, const float* __restrict__ We,
                      const float* __restrict__ e, float* __restrict__ WQK,
                      float* __restrict__ cvec, int F) {
  if ((int)blockIdx.x == (RREL * F * 16) / 256) {
    int j = threadIdx.x;
    if (j < NHEAD) {
      float acc = 0.f;
      for (int h2 = 0; h2 < HD; ++h2) acc += We[h2] * e[h2 * NHEAD + j];
      cvec[j] = acc;
    }
    return;
  }
  int g = blockIdx.x * 256 + threadIdx.x;
  int j = g & 15;
  int rf = g >> 4;  // r*F + f
  int f = rf % F;
  const float* wrow = W + (size_t)rf * HD;
  const float* qk = ((j < 8) ? q : k) + (j & 7);
  float acc = 0.f;
  for (int h = 0; h < HD; ++h) acc += wrow[h] * qk[(size_t)h * NHEAD];
  WQK[(size_t)f * 128 + (rf / F) * 16 + j] = acc;
}

// ---------- split-bf16 operand builders (2-term: A=[hi|lo], B=[hi;hi]) ----
__global__ void k_asplit(const float* __restrict__ in, unsigned short* __restrict__ A2,
                         int F) {
  long idx = (long)blockIdx.x * 256 + threadIdx.x;  // over NN * F/4
  long total = (long)NN * (F >> 2);
  if (idx >= total) return;
  int row = (int)(idx / (F >> 2));
  int c4 = (int)(idx % (F >> 2)) << 2;
  float4 v = *(const float4*)&in[(size_t)row * F + c4];
  ushort4 hi, lo;
  hi.x = f2bf(v.x); hi.y = f2bf(v.y); hi.z = f2bf(v.z); hi.w = f2bf(v.w);
  lo.x = f2bf(v.x - bf2f(hi.x)); lo.y = f2bf(v.y - bf2f(hi.y));
  lo.z = f2bf(v.z - bf2f(hi.z)); lo.w = f2bf(v.w - bf2f(hi.w));
  unsigned short* base = A2 + (size_t)row * 2 * F;
  *(ushort4*)&base[c4] = hi;
  *(ushort4*)&base[F + c4] = lo;
}

// W: [R][F][512] f32 -> BT: flattened [4096 cols][2F] bf16 (col-major B)
__global__ __launch_bounds__(256) void k_bsplit(const float* __restrict__ W,
                                                unsigned short* __restrict__ BT, int F) {
  int f0 = blockIdx.x * 64, c0 = blockIdx.y * 64, r = blockIdx.z;
  __shared__ float tile[64][65];
  int tid = threadIdx.x;
  int i0 = tid >> 6;   // 0..3
  int j = tid & 63;
  const float* Wr = W + (size_t)r * F * 512;
  for (int i = i0; i < 64; i += 4)
    tile[i][j] = Wr[(size_t)(f0 + i) * 512 + c0 + j];
  __syncthreads();
  unsigned short* Br = BT + (size_t)r * 512 * 2 * F;
  for (int c = i0; c < 64; c += 4) {
    float v = tile[j][c];  // W[r][f0+j][c0+c]
    unsigned short hi = f2bf(v);
    unsigned short* dst = Br + (size_t)(c0 + c) * 2 * F + f0 + j;
    dst[0] = hi; dst[F] = hi;
  }
}

// ---------- MFMA GEMM: C = A2[16128 x Kp] @ BT^T (N=4096 flat) ----------
// BM=128, BN=256, BK=32, 4 waves (each 128x64), 2 LDS buffers (48 KB total)
// -> 2 blocks/CU: per-tile vmcnt(0) drain in one block overlaps the other
// block's MFMA cluster (cross-block latency hiding instead of intra-block
// phasing). Fragment-ordered LDS -> conflict-free ds_read_b128.
__global__ __launch_bounds__(256, 2) void k_mgemm(const unsigned short* __restrict__ A2,
                                                  const unsigned short* __restrict__ BT,
                                                  unsigned short* __restrict__ Ct,
                                                  int Kp) {
  const int bid = blockIdx.x;
  const int v = (bid & 7) * 252 + (bid >> 3);   // 2016 = 8*252, bijective
  const int mb = v >> 4;                        // 0..125 (m slow)
  const int nb = v & 15;                        // n fastest: A-panel L2-reuse
  const int m0 = mb << 7;
  const int n0 = nb << 8;

  __shared__ __align__(16) unsigned short smem[24576];  // 48 KB
  // per buf (12288 shorts): A frags 0..7 at [f*512]; B frags 0..15 at [4096+g*512]

  const int tid = threadIdx.x;
  const int wid = tid >> 6;     // 0..3 = n-quarter
  const int lane = tid & 63;
  const int rlow = lane & 15;
  const int kch = lane >> 4;    // 0..3

  const unsigned short* sA[2];
  const unsigned short* sB[4];
  int dA[2], dB[4];
#pragma unroll
  for (int p = 0; p < 2; ++p) {
    int f = wid * 2 + p;        // 0..7
    sA[p] = A2 + (size_t)(m0 + f * 16 + rlow) * Kp + kch * 8;
    dA[p] = f * 512;
  }
#pragma unroll
  for (int p = 0; p < 4; ++p) {
    int g = wid * 4 + p;        // 0..15
    sB[p] = BT + (size_t)(n0 + g * 16 + rlow) * Kp + kch * 8;
    dB[p] = 4096 + g * 512;
  }

  f32x4 acc[8][4] = {};
  const int nt = Kp >> 5;

  // prologue: stage tile 0 into buffer 0
#pragma unroll
  for (int p = 0; p < 2; ++p) g2lds16(sA[p], &smem[dA[p]]);
#pragma unroll
  for (int p = 0; p < 4; ++p) g2lds16(sB[p], &smem[dB[p]]);

  for (int u = 0; u < nt; ++u) {
    asm volatile("s_waitcnt vmcnt(0)" ::: "memory");
    __builtin_amdgcn_s_barrier();
    asm volatile("" ::: "memory");
    const int buf = u & 1;
    if (u + 1 < nt) {
      const int ko = (u + 1) << 5;
      const int bo = (buf ^ 1) * 12288;
#pragma unroll
      for (int p = 0; p < 2; ++p) g2lds16(sA[p] + ko, &smem[bo + dA[p]]);
#pragma unroll
      for (int p = 0; p < 4; ++p) g2lds16(sB[p] + ko, &smem[bo + dB[p]]);
    }
    const unsigned short* Ab = smem + buf * 12288;
    const unsigned short* Bb = Ab + 4096;
    bf16x8 af[8], bv[4];
#pragma unroll
    for (int i = 0; i < 8; ++i)
      af[i] = *(const bf16x8*)&Ab[i * 512 + lane * 8];
#pragma unroll
    for (int j = 0; j < 4; ++j)
      bv[j] = *(const bf16x8*)&Bb[(wid * 4 + j) * 512 + lane * 8];
    __builtin_amdgcn_s_setprio(1);
#pragma unroll
    for (int i = 0; i < 8; ++i)
#pragma unroll
      for (int j = 0; j < 4; ++j)
        acc[i][j] = __builtin_amdgcn_mfma_f32_16x16x32_bf16(af[i], bv[j],
                                                            acc[i][j], 0, 0, 0);
    __builtin_amdgcn_s_setprio(0);
  }

  // ---- epilogue: per-wave private LDS transpose (no cross-wave sync) ----
  __syncthreads();
  float* epsW = (float*)smem + wid * 1344;  // 64 cols x 21 pad floats
  const int rowL = lane & 15;
  const int cseg = lane >> 4;
  const int colfull0 = n0 + wid * 64;
  const int rr = colfull0 >> 9;
  const int hbase = (colfull0 & 511) + cseg * 16;
#pragma unroll
  for (int i = 0; i < 8; ++i) {
#pragma unroll
    for (int j = 0; j < 4; ++j)
      *(f32x4*)&epsW[(j * 16 + rlow) * 21 + kch * 4] = acc[i][j];
    float vals[16];
#pragma unroll
    for (int c = 0; c < 16; ++c) vals[c] = epsW[(cseg * 16 + c) * 21 + rowL];
    const int rowg = m0 + i * 16 + rowL;
    unsigned short* dst = Ct + ((size_t)rr * MPAD + rowg) * HD + hbase;
    uint4 w0, w1;
    w0.x = (u32)f2bf(vals[0])  | ((u32)f2bf(vals[1])  << 16);
    w0.y = (u32)f2bf(vals[2])  | ((u32)f2bf(vals[3])  << 16);
    w0.z = (u32)f2bf(vals[4])  | ((u32)f2bf(vals[5])  << 16);
    w0.w = (u32)f2bf(vals[6])  | ((u32)f2bf(vals[7])  << 16);
    w1.x = (u32)f2bf(vals[8])  | ((u32)f2bf(vals[9])  << 16);
    w1.y = (u32)f2bf(vals[10]) | ((u32)f2bf(vals[11]) << 16);
    w1.z = (u32)f2bf(vals[12]) | ((u32)f2bf(vals[13]) << 16);
    w1.w = (u32)f2bf(vals[14]) | ((u32)f2bf(vals[15]) << 16);
    *(uint4*)dst = w0;
    *(uint4*)(dst + 8) = w1;
  }
}

// ---------- small fp32 GEMM (layer-1 qkbuf): C = A @ B, B:[F][128] -------
__global__ __launch_bounds__(256) void k_gemm(const float* __restrict__ A,
                                              const float* __restrict__ B,
                                              float* __restrict__ C, int F) {
  const int m0 = blockIdx.x * 128;
  __shared__ float As[16][132];
  __shared__ float Bs[16][132];
  const int tid = threadIdx.x;
  const int arow = tid >> 2;
  const int acol = (tid & 3) << 2;
  const int brow = tid >> 5;
  const int bcol = (tid & 31) << 2;
  const int tr = ((tid >> 4) & 15) << 2;
  const int tc = (tid & 15) << 2;
  float acc[8][8] = {};
  for (int k0 = 0; k0 < F; k0 += 16) {
    float4 a0 = *(const float4*)&A[(size_t)(m0 + arow) * F + k0 + acol];
    float4 a1 = *(const float4*)&A[(size_t)(m0 + arow + 64) * F + k0 + acol];
    float4 b0 = *(const float4*)&B[(size_t)(k0 + brow) * 128 + bcol];
    float4 b1 = *(const float4*)&B[(size_t)(k0 + brow + 8) * 128 + bcol];
    As[acol + 0][arow] = a0.x; As[acol + 1][arow] = a0.y;
    As[acol + 2][arow] = a0.z; As[acol + 3][arow] = a0.w;
    As[acol + 0][arow + 64] = a1.x; As[acol + 1][arow + 64] = a1.y;
    As[acol + 2][arow + 64] = a1.z; As[acol + 3][arow + 64] = a1.w;
    *(float4*)&Bs[brow][bcol] = b0;
    *(float4*)&Bs[brow + 8][bcol] = b1;
    __syncthreads();
#pragma unroll
    for (int k = 0; k < 16; ++k) {
      float a[8], b[8];
      *(float4*)(a) = *(const float4*)&As[k][tr];
      *(float4*)(a + 4) = *(const float4*)&As[k][tr + 64];
      *(float4*)(b) = *(const float4*)&Bs[k][tc];
      *(float4*)(b + 4) = *(const float4*)&Bs[k][tc + 64];
#pragma unroll
      for (int i = 0; i < 8; ++i)
#pragma unroll
        for (int j = 0; j < 8; ++j)
          acc[i][j] = fmaf(a[i], b[j], acc[i][j]);
    }
    __syncthreads();
  }
#pragma unroll
  for (int i = 0; i < 8; ++i) {
    int row = m0 + tr + ((i < 4) ? i : (60 + i));
    *(float4*)&C[(size_t)row * 128 + tc] = make_float4(acc[i][0], acc[i][1], acc[i][2], acc[i][3]);
    *(float4*)&C[(size_t)row * 128 + tc + 64] = make_float4(acc[i][4], acc[i][5], acc[i][6], acc[i][7]);
  }
}

// ---------- layer-2 qkbuf GEMM: A from hi|lo bf16 pairs (stride 1024) -----
__global__ __launch_bounds__(256) void k_gemm2(const unsigned short* __restrict__ A2,
                                               const float* __restrict__ B,
                                               float* __restrict__ C) {
  const int m0 = blockIdx.x * 128;
  __shared__ float As[16][132];
  __shared__ float Bs[16][132];
  const int tid = threadIdx.x;
  const int arow = tid >> 2;
  const int acol = (tid & 3) << 2;
  const int brow = tid >> 5;
  const int bcol = (tid & 31) << 2;
  const int tr = ((tid >> 4) & 15) << 2;
  const int tc = (tid & 15) << 2;
  float acc[8][8] = {};
  for (int k0 = 0; k0 < 512; k0 += 16) {
    ushort4 h0 = *(const ushort4*)&A2[(size_t)(m0 + arow) * 1024 + k0 + acol];
    ushort4 l0 = *(const ushort4*)&A2[(size_t)(m0 + arow) * 1024 + 512 + k0 + acol];
    ushort4 h1 = *(const ushort4*)&A2[(size_t)(m0 + arow + 64) * 1024 + k0 + acol];
    ushort4 l1 = *(const ushort4*)&A2[(size_t)(m0 + arow + 64) * 1024 + 512 + k0 + acol];
    float4 a0 = make_float4(bf2f(h0.x) + bf2f(l0.x), bf2f(h0.y) + bf2f(l0.y),
                            bf2f(h0.z) + bf2f(l0.z), bf2f(h0.w) + bf2f(l0.w));
    float4 a1 = make_float4(bf2f(h1.x) + bf2f(l1.x), bf2f(h1.y) + bf2f(l1.y),
                            bf2f(h1.z) + bf2f(l1.z), bf2f(h1.w) + bf2f(l1.w));
    float4 b0 = *(const float4*)&B[(size_t)(k0 + brow) * 128 + bcol];
    float4 b1 = *(const float4*)&B[(size_t)(k0 + brow + 8) * 128 + bcol];
    As[acol + 0][arow] = a0.x; As[acol + 1][arow] = a0.y;
    As[acol + 2][arow] = a0.z; As[acol + 3][arow] = a0.w;
    As[acol + 0][arow + 64] = a1.x; As[acol + 1][arow + 64] = a1.y;
    As[acol + 2][arow + 64] = a1.z; As[acol + 3][arow + 64] = a1.w;
    *(float4*)&Bs[brow][bcol] = b0;
    *(float4*)&Bs[brow + 8][bcol] = b1;
    __syncthreads();
#pragma unroll
    for (int k = 0; k < 16; ++k) {
      float a[8], b[8];
      *(float4*)(a) = *(const float4*)&As[k][tr];
      *(float4*)(a + 4) = *(const float4*)&As[k][tr + 64];
      *(float4*)(b) = *(const float4*)&Bs[k][tc];
      *(float4*)(b + 4) = *(const float4*)&Bs[k][tc + 64];
#pragma unroll
      for (int i = 0; i < 8; ++i)
#pragma unroll
        for (int j = 0; j < 8; ++j)
          acc[i][j] = fmaf(a[i], b[j], acc[i][j]);
    }
    __syncthreads();
  }
#pragma unroll
  for (int i = 0; i < 8; ++i) {
    int row = m0 + tr + ((i < 4) ? i : (60 + i));
    *(float4*)&C[(size_t)row * 128 + tc] = make_float4(acc[i][0], acc[i][1], acc[i][2], acc[i][3]);
    *(float4*)&C[(size_t)row * 128 + tc + 64] = make_float4(acc[i][4], acc[i][5], acc[i][6], acc[i][7]);
  }
}

// ---------- fused attention: one WAVE per dst node, online rescale-skip ---
template <int CONCAT>
__global__ __launch_bounds__(256) void k_attn(const unsigned short* __restrict__ t,
    const float* __restrict__ qkbuf, const float* __restrict__ cvec,
    const int* __restrict__ rowptr, const int* __restrict__ csr_src,
    const int* __restrict__ csr_et, const float* __restrict__ csr_ea,
    const float* __restrict__ bias, float* __restrict__ out,
    unsigned short* __restrict__ A2out) {
  const int wv = threadIdx.x >> 6;
  const int lane = threadIdx.x & 63;
  const int n = blockIdx.x * 4 + wv;
  const int h = lane >> 3;
  const int c0 = lane << 3;  // 8 cols per lane
  const int e0 = rowptr[n], e1 = rowptr[n + 1];
  const float ch = cvec[h];
  const float* qrow = qkbuf + (size_t)n * 128;
  float m = -1e30f, l = 0.f;
  float acc[8] = {};
  for (int e = e0; e < e1; ++e) {
    const int s = csr_src[e];
    const int r = csr_et[e];
    const float a = csr_ea[e];
    float logit = qrow[r * 16 + h] + qkbuf[(size_t)s * 128 + r * 16 + 8 + h] + a * ch;
    logit = (logit > 0.f) ? logit : NEG * logit;
    const uint4 tv = *(const uint4*)&t[((size_t)r * MPAD + s) * HD + c0];
    float p;
    if (logit <= m) {
      p = __expf(logit - m);
    } else {
      const float sc = __expf(m - logit);
      l *= sc;
#pragma unroll
      for (int c = 0; c < 8; ++c) acc[c] *= sc;
      m = logit;
      p = 1.f;
    }
    l += p;
    acc[0] = fmaf(p, __uint_as_float((tv.x & 0xffffu) << 16), acc[0]);
    acc[1] = fmaf(p, __uint_as_float(tv.x & 0xffff0000u), acc[1]);
    acc[2] = fmaf(p, __uint_as_float((tv.y & 0xffffu) << 16), acc[2]);
    acc[3] = fmaf(p, __uint_as_float(tv.y & 0xffff0000u), acc[3]);
    acc[4] = fmaf(p, __uint_as_float((tv.z & 0xffffu) << 16), acc[4]);
    acc[5] = fmaf(p, __uint_as_float(tv.z & 0xffff0000u), acc[5]);
    acc[6] = fmaf(p, __uint_as_float((tv.w & 0xffffu) << 16), acc[6]);
    acc[7] = fmaf(p, __uint_as_float(tv.w & 0xffff0000u), acc[7]);
  }
  const float inv = 1.f / (l + 1e-16f);
  if (CONCAT) {
    unsigned short his[8], los[8];
#pragma unroll
    for (int c = 0; c < 8; ++c) {
      const float vv = fmaf(acc[c], inv, bias[c0 + c]);
      const unsigned short hi = f2bf(vv);
      his[c] = hi;
      los[c] = f2bf(vv - bf2f(hi));
    }
    uint4 wh, wl;
    wh.x = (u32)his[0] | ((u32)his[1] << 16);
    wh.y = (u32)his[2] | ((u32)his[3] << 16);
    wh.z = (u32)his[4] | ((u32)his[5] << 16);
    wh.w = (u32)his[6] | ((u32)his[7] << 16);
    wl.x = (u32)los[0] | ((u32)los[1] << 16);
    wl.y = (u32)los[2] | ((u32)los[3] << 16);
    wl.z = (u32)los[4] | ((u32)los[5] << 16);
    wl.w = (u32)los[6] | ((u32)los[7] << 16);
    *(uint4*)&A2out[(size_t)n * 1024 + c0] = wh;
    *(uint4*)&A2out[(size_t)n * 1024 + 512 + c0] = wl;
  } else {
    __shared__ float sm[4][HD];
#pragma unroll
    for (int c = 0; c < 8; ++c) sm[wv][c0 + c] = acc[c] * inv;
    __syncthreads();
    const int d = lane;
    float s = 0.f;
#pragma unroll
    for (int hh = 0; hh < NHEAD; ++hh) s += sm[wv][hh * 64 + d];
    out[(size_t)n * DOUT + d] = s * 0.125f + bias[d];
  }
}

// ---------- launch ----------
static void run_pipeline(const float* x, const int* ei, const int* et, const float* ea,
                         const float* W1, const float* q1, const float* k1,
                         const float* We1, const float* e1, const float* b1,
                         const float* W2, const float* q2, const float* k2,
                         const float* We2, const float* e2, const float* b2,
                         float* out, float* qkbuf, float* WQK,
                         unsigned short* A2, unsigned short* BT,
                         float* cvec, int* meta, int* deg, int* rowptr,
                         int* fill, int* csr_src, int* csr_et, float* csr_ea,
                         unsigned short* t, hipStream_t stream) {
  (void)hipMemsetAsync(meta, 0, 4, stream);
  (void)hipMemsetAsync(deg, 0, (size_t)NN * 4, stream);
  k_hist<<<(ETOT + 255) / 256, 256, 0, stream>>>(ei, et, deg, meta);
  k_scan<<<1, 1024, 0, stream>>>(deg, rowptr, fill);
  k_scatter<<<(ETOT + 255) / 256, 256, 0, stream>>>(ei, et, ea, meta, fill,
                                                    csr_src, csr_et, csr_ea);
  // layer 1 (F=256, Kp=512): A2 row stride 512
  k_wqk<<<RREL * 256 * 16 / 256 + 1, 256, 0, stream>>>(W1, q1, k1, We1, e1, WQK,
                                                       cvec, 256);
  k_asplit<<<(NN * 64 + 255) / 256, 256, 0, stream>>>(x, A2, 256);
  k_bsplit<<<dim3(4, 8, RREL), 256, 0, stream>>>(W1, BT, 256);
  k_mgemm<<<2016, 256, 0, stream>>>(A2, BT, t, 512);
  k_gemm<<<125, 256, 0, stream>>>(x, WQK, qkbuf, 256);
  k_attn<1><<<NN / 4, 256, 0, stream>>>(t, qkbuf, cvec, rowptr, csr_src, csr_et,
                                        csr_ea, b1, nullptr, A2);  // A2 stride 1024
  // layer 2 (F=512, Kp=1024): A2 written by attn<1>
  k_wqk<<<RREL * HD * 16 / 256 + 1, 256, 0, stream>>>(W2, q2, k2, We2, e2, WQK,
                                                      cvec, HD);
  k_bsplit<<<dim3(8, 8, RREL), 256, 0, stream>>>(W2, BT, HD);
  k_mgemm<<<2016, 256, 0, stream>>>(A2, BT, t, 1024);
  k_gemm2<<<125, 256, 0, stream>>>(A2, WQK, qkbuf);
  k_attn<0><<<NN / 4, 256, 0, stream>>>(t, qkbuf, cvec, rowptr, csr_src, csr_et,
                                        csr_ea, b2, out, nullptr);
}

extern "C" void kernel_launch(void* const* d_in, const int* in_sizes, int n_in,
                              void* d_out, int out_size, void* d_ws, size_t ws_size,
                              hipStream_t stream) {
  const float* x   = (const float*)d_in[0];
  const int*   ei  = (const int*)d_in[1];
  const int*   et  = (const int*)d_in[2];
  const float* ea  = (const float*)d_in[3];
  const float* W1  = (const float*)d_in[4];
  const float* q1  = (const float*)d_in[5];
  const float* k1  = (const float*)d_in[6];
  const float* We1 = (const float*)d_in[7];
  const float* e1  = (const float*)d_in[8];
  const float* b1  = (const float*)d_in[9];
  const float* W2  = (const float*)d_in[10];
  const float* q2  = (const float*)d_in[11];
  const float* k2  = (const float*)d_in[12];
  const float* We2 = (const float*)d_in[13];
  const float* e2  = (const float*)d_in[14];
  const float* b2  = (const float*)d_in[15];
  float* out = (float*)d_out;

  char* w = (char*)d_ws;
  auto alloc = [&](size_t bytes) {
    char* p = w;
    w += (bytes + 255) & ~(size_t)255;
    return p;
  };
  float* qkbuf  = (float*)alloc((size_t)NN * 128 * 4);
  float* WQK    = (float*)alloc((size_t)HD * 128 * 4);
  unsigned short* A2 = (unsigned short*)alloc((size_t)MPAD * 2 * HD * 2);
  unsigned short* BT = (unsigned short*)alloc((size_t)RREL * HD * 2 * HD * 2);
  float* cvec   = (float*)alloc(64);
  int*   meta   = (int*)alloc(64);
  int*   deg    = (int*)alloc((size_t)NN * 4);
  int*   rowptr = (int*)alloc((size_t)(NN + 1) * 4);
  int*   fill   = (int*)alloc((size_t)NN * 4);
  int*   csr_src= (int*)alloc((size_t)ETOT * 4);
  int*   csr_et = (int*)alloc((size_t)ETOT * 4);
  float* csr_ea = (float*)alloc((size_t)ETOT * 4);
  unsigned short* t = (unsigned short*)alloc((size_t)RREL * MPAD * HD * 2);
  (void)ws_size;

  run_pipeline(x, ei, et, ea, W1, q1, k1, We1, e1, b1,
               W2, q2, k2, We2, e2, b2, out, qkbuf, WQK, A2, BT,
               cvec, meta, deg, rowptr, fill, csr_src, csr_et, csr_ea,
               t, stream);
}

// Round 13
// 596.425 us; speedup vs baseline: 1.1618x; 1.1618x over previous
//
#include <hip/hip_runtime.h>
#include <hip/hip_bf16.h>
#include <cstdint>
#include <cstddef>

#define NN 16000
#define MPAD 16128
#define EE 256000
#define ETOT (EE + NN)
#define RREL 8
#define NHEAD 8
#define DOUT 64
#define HD 512
#define NEG 0.2f
#define NMAIN 1008

typedef unsigned int u32;
typedef short bf16x8 __attribute__((ext_vector_type(8)));
typedef float f32x4 __attribute__((ext_vector_type(4)));

// ---------- helpers ----------
__device__ inline unsigned short f2bf(float f) {
  u32 i = __float_as_uint(f);
  u32 r = (i + 0x7fff + ((i >> 16) & 1)) >> 16;  // RNE, finite values
  return (unsigned short)r;
}
__device__ inline float bf2f(unsigned short h) {
  return __uint_as_float((u32)h << 16);
}
__device__ inline void g2lds16(const void* g, void* lds) {
  __builtin_amdgcn_global_load_lds(
      (const __attribute__((address_space(1))) unsigned int*)g,
      (__attribute__((address_space(3))) unsigned int*)lds, 16, 0, 0);
}

// ---------- preprocessing ----------
__global__ void k_hist(const int* __restrict__ ei, const int* __restrict__ et,
                       int* __restrict__ deg, int* __restrict__ meta) {
  int e = blockIdx.x * 256 + threadIdx.x;
  if (e >= ETOT) return;
  int dst;
  if (e < EE) { dst = ei[EE + e]; atomicMax(&meta[0], et[e]); }
  else dst = e - EE;
  atomicAdd(&deg[dst], 1);
}

// 16 elems/thread serial prefix + single 1024-wide block scan
__global__ __launch_bounds__(1024) void k_scan(const int* __restrict__ deg,
                                               int* __restrict__ rowptr,
                                               int* __restrict__ fill) {
  __shared__ int sm[1024];
  const int tid = threadIdx.x;
  const int base = tid * 16;
  int local[16];
  int s = 0;
#pragma unroll
  for (int i = 0; i < 16; ++i) {
    int idx = base + i;
    int v = (idx < NN) ? deg[idx] : 0;
    local[i] = s;
    s += v;
  }
  sm[tid] = s;
  __syncthreads();
  for (int off = 1; off < 1024; off <<= 1) {
    int t = (tid >= off) ? sm[tid - off] : 0;
    __syncthreads();
    sm[tid] += t;
    __syncthreads();
  }
  const int pre = (tid > 0) ? sm[tid - 1] : 0;
#pragma unroll
  for (int i = 0; i < 16; ++i) {
    int idx = base + i;
    if (idx < NN) { rowptr[idx] = pre + local[i]; fill[idx] = pre + local[i]; }
  }
  if (tid == 1023) rowptr[NN] = sm[1023];
}

__global__ void k_scatter(const int* __restrict__ ei, const int* __restrict__ et,
                          const float* __restrict__ ea, const int* __restrict__ meta,
                          int* __restrict__ fill, int* __restrict__ csr_src,
                          int* __restrict__ csr_et, float* __restrict__ csr_ea) {
  int e = blockIdx.x * 256 + threadIdx.x;
  if (e >= ETOT) return;
  int src, dst, r; float a;
  if (e < EE) { src = ei[e]; dst = ei[EE + e]; r = et[e]; a = ea[e]; }
  else { src = dst = e - EE; r = (meta[0] + 1) & (RREL - 1); a = 0.5f; }
  int pos = atomicAdd(&fill[dst], 1);
  csr_src[pos] = src; csr_et[pos] = r; csr_ea[pos] = a;
}

// ---------- per-layer small precomputes ----------
// WQKT[col][k'] (bf16, split form [hi;hi]); col = r*16+j; extra block -> cvec
__global__ void k_wqk(const float* __restrict__ W, const float* __restrict__ q,
                      const float* __restrict__ k, const float* __restrict__ We,
                      const float* __restrict__ e, unsigned short* __restrict__ WQKT,
                      float* __restrict__ cvec, int F) {
  if ((int)blockIdx.x == (RREL * F * 16) / 256) {
    int j = threadIdx.x;
    if (j < NHEAD) {
      float acc = 0.f;
      for (int h2 = 0; h2 < HD; ++h2) acc += We[h2] * e[h2 * NHEAD + j];
      cvec[j] = acc;
    }
    return;
  }
  int g = blockIdx.x * 256 + threadIdx.x;
  int j = g & 15;
  int rf = g >> 4;  // r*F + f
  int f = rf % F;
  const float* wrow = W + (size_t)rf * HD;
  const float* qk = ((j < 8) ? q : k) + (j & 7);
  float acc = 0.f;
  for (int h = 0; h < HD; ++h) acc += wrow[h] * qk[(size_t)h * NHEAD];
  const int col = (rf / F) * 16 + j;  // 0..127
  const unsigned short hi = f2bf(acc);
  WQKT[(size_t)col * 2 * F + f] = hi;
  WQKT[(size_t)col * 2 * F + F + f] = hi;
}

// ---------- split-bf16 operand builders (2-term: A=[hi|lo], B=[hi;hi]) ----
__global__ void k_asplit(const float* __restrict__ in, unsigned short* __restrict__ A2,
                         int F) {
  long idx = (long)blockIdx.x * 256 + threadIdx.x;  // over NN * F/4
  long total = (long)NN * (F >> 2);
  if (idx >= total) return;
  int row = (int)(idx / (F >> 2));
  int c4 = (int)(idx % (F >> 2)) << 2;
  float4 v = *(const float4*)&in[(size_t)row * F + c4];
  ushort4 hi, lo;
  hi.x = f2bf(v.x); hi.y = f2bf(v.y); hi.z = f2bf(v.z); hi.w = f2bf(v.w);
  lo.x = f2bf(v.x - bf2f(hi.x)); lo.y = f2bf(v.y - bf2f(hi.y));
  lo.z = f2bf(v.z - bf2f(hi.z)); lo.w = f2bf(v.w - bf2f(hi.w));
  unsigned short* base = A2 + (size_t)row * 2 * F;
  *(ushort4*)&base[c4] = hi;
  *(ushort4*)&base[F + c4] = lo;
}

// W: [R][F][512] f32 -> BT: flattened [4096 cols][2F] bf16 (col-major B)
__global__ __launch_bounds__(256) void k_bsplit(const float* __restrict__ W,
                                                unsigned short* __restrict__ BT, int F) {
  int f0 = blockIdx.x * 64, c0 = blockIdx.y * 64, r = blockIdx.z;
  __shared__ float tile[64][65];
  int tid = threadIdx.x;
  int i0 = tid >> 6;   // 0..3
  int j = tid & 63;
  const float* Wr = W + (size_t)r * F * 512;
  for (int i = i0; i < 64; i += 4)
    tile[i][j] = Wr[(size_t)(f0 + i) * 512 + c0 + j];
  __syncthreads();
  unsigned short* Br = BT + (size_t)r * 512 * 2 * F;
  for (int c = i0; c < 64; c += 4) {
    float v = tile[j][c];  // W[r][f0+j][c0+c]
    unsigned short hi = f2bf(v);
    unsigned short* dst = Br + (size_t)(c0 + c) * 2 * F + f0 + j;
    dst[0] = hi; dst[F] = hi;
  }
}

// ---------- MFMA GEMM (round-9 best structure) + fused qk blocks ----------
// bid < NMAIN: C = A2[16128 x Kp] @ BT^T (N=4096), bf16 t output.
// bid >= NMAIN: 63 blocks computing qkbuf = A2 @ WQKT^T (N=256, cols<128
// stored f32). Same staging/loop; blocks fill idle CUs during the tail.
// BM=BN=256, BK=32, 8 waves (2M x 4N), 3 LDS buffers (96 KB), prefetch
// distance 2, counted vmcnt(4). Fragment-ordered LDS -> conflict-free.
__global__ __launch_bounds__(512, 2) void k_mgemm(const unsigned short* __restrict__ A2,
                                                  const unsigned short* __restrict__ BT,
                                                  const unsigned short* __restrict__ WQKT,
                                                  unsigned short* __restrict__ Ct,
                                                  float* __restrict__ qkbuf,
                                                  int Kp) {
  const int bid = blockIdx.x;
  const bool isqk = (bid >= NMAIN);
  int m0, n0;
  const unsigned short* Bbase;
  if (!isqk) {
    const int v = (bid & 7) * 126 + (bid >> 3);   // 1008 = 8*126, bijective
    m0 = (v >> 4) << 8;
    n0 = (v & 15) << 8;
    Bbase = BT;
  } else {
    m0 = (bid - NMAIN) << 8;
    n0 = 0;
    Bbase = WQKT;
  }

  __shared__ __align__(16) unsigned short smem[49152];  // 96 KB
  // A: buf b at [b*8192], 16 frags x 512 shorts; B: at [24576 + b*8192]

  const int tid = threadIdx.x;
  const int wid = tid >> 6;
  const int lane = tid & 63;
  const int wr = wid >> 2;     // 0..1 (m half)
  const int wc = wid & 3;      // 0..3 (n quarter)
  const int rlow = lane & 15;
  const int kch = lane >> 4;   // 0..3

  const unsigned short* srcA[2];
  const unsigned short* srcB[2];
  int dstOff[2];
#pragma unroll
  for (int p = 0; p < 2; ++p) {
    int fr = (p << 3) + wid;   // 0..15
    srcA[p] = A2 + (size_t)(m0 + fr * 16 + rlow) * Kp + kch * 8;
    srcB[p] = Bbase + (size_t)(n0 + fr * 16 + rlow) * Kp + kch * 8;
    dstOff[p] = fr * 512;
  }

  f32x4 acc[8][4] = {};
  const int nt = Kp >> 5;

  // prologue: stage tiles 0,1 into buffers 0,1 (8 vm-ops per thread)
#pragma unroll
  for (int tp = 0; tp < 2; ++tp) {
    const int ko = tp << 5;
#pragma unroll
    for (int p = 0; p < 2; ++p) {
      g2lds16(srcA[p] + ko, &smem[tp * 8192 + dstOff[p]]);
      g2lds16(srcB[p] + ko, &smem[24576 + tp * 8192 + dstOff[p]]);
    }
  }

  int buf = 0;
  for (int u = 0; u < nt; ++u) {
    if (u + 1 < nt)
      asm volatile("s_waitcnt vmcnt(4)" ::: "memory");
    else
      asm volatile("s_waitcnt vmcnt(0)" ::: "memory");
    __builtin_amdgcn_s_barrier();
    asm volatile("" ::: "memory");
    if (u + 2 < nt) {
      int nb2 = buf + 2; if (nb2 >= 3) nb2 -= 3;
      const int ko = (u + 2) << 5;
#pragma unroll
      for (int p = 0; p < 2; ++p) {
        g2lds16(srcA[p] + ko, &smem[nb2 * 8192 + dstOff[p]]);
        g2lds16(srcB[p] + ko, &smem[24576 + nb2 * 8192 + dstOff[p]]);
      }
    }
    const unsigned short* Ab = smem + buf * 8192;
    const unsigned short* Bb = smem + 24576 + buf * 8192;
    bf16x8 af[8], bv[4];
#pragma unroll
    for (int i = 0; i < 8; ++i)
      af[i] = *(const bf16x8*)&Ab[(wr * 8 + i) * 512 + lane * 8];
#pragma unroll
    for (int j = 0; j < 4; ++j)
      bv[j] = *(const bf16x8*)&Bb[(wc * 4 + j) * 512 + lane * 8];
    __builtin_amdgcn_s_setprio(1);
#pragma unroll
    for (int i = 0; i < 8; ++i)
#pragma unroll
      for (int j = 0; j < 4; ++j)
        acc[i][j] = __builtin_amdgcn_mfma_f32_16x16x32_bf16(af[i], bv[j],
                                                            acc[i][j], 0, 0, 0);
    __builtin_amdgcn_s_setprio(0);
    buf = (buf == 2) ? 0 : buf + 1;
  }

  if (!isqk) {
    // ---- epilogue: per-wave private LDS transpose, bf16 t output ----
    __syncthreads();
    float* epsW = (float*)smem + wid * 1344;  // 64 cols x 21 pad
    const int rowL = lane & 15;
    const int cseg = lane >> 4;
    const int colfull0 = n0 + wc * 64;
    const int rr = colfull0 >> 9;
    const int hbase = (colfull0 & 511) + cseg * 16;
#pragma unroll
    for (int i = 0; i < 8; ++i) {
#pragma unroll
      for (int j = 0; j < 4; ++j)
        *(f32x4*)&epsW[(j * 16 + rlow) * 21 + kch * 4] = acc[i][j];
      float vals[16];
#pragma unroll
      for (int c = 0; c < 16; ++c) vals[c] = epsW[(cseg * 16 + c) * 21 + rowL];
      const int rowg = m0 + wr * 128 + i * 16 + rowL;
      unsigned short* dst = Ct + ((size_t)rr * MPAD + rowg) * HD + hbase;
      uint4 w0, w1;
      w0.x = (u32)f2bf(vals[0])  | ((u32)f2bf(vals[1])  << 16);
      w0.y = (u32)f2bf(vals[2])  | ((u32)f2bf(vals[3])  << 16);
      w0.z = (u32)f2bf(vals[4])  | ((u32)f2bf(vals[5])  << 16);
      w0.w = (u32)f2bf(vals[6])  | ((u32)f2bf(vals[7])  << 16);
      w1.x = (u32)f2bf(vals[8])  | ((u32)f2bf(vals[9])  << 16);
      w1.y = (u32)f2bf(vals[10]) | ((u32)f2bf(vals[11]) << 16);
      w1.z = (u32)f2bf(vals[12]) | ((u32)f2bf(vals[13]) << 16);
      w1.w = (u32)f2bf(vals[14]) | ((u32)f2bf(vals[15]) << 16);
      *(uint4*)dst = w0;
      *(uint4*)(dst + 8) = w1;
    }
  } else {
    // ---- qk epilogue: direct f32 stores for cols < 128 ----
    if (wc < 2) {
#pragma unroll
      for (int i = 0; i < 8; ++i) {
        const int row0 = m0 + wr * 128 + i * 16 + kch * 4;
#pragma unroll
        for (int j = 0; j < 4; ++j) {
          const int col = wc * 64 + j * 16 + rlow;
#pragma unroll
          for (int q = 0; q < 4; ++q) {
            const int row = row0 + q;
            if (row < NN) qkbuf[(size_t)row * 128 + col] = acc[i][j][q];
          }
        }
      }
    }
  }
}

// ---------- fused attention: one WAVE per dst node, online rescale-skip ---
// 2-deep software pipeline: next edge's csr/t-row/k-logit loads issue before
// the current edge's exp/FMA chain.
template <int CONCAT>
__global__ __launch_bounds__(256) void k_attn(const unsigned short* __restrict__ t,
    const float* __restrict__ qkbuf, const float* __restrict__ cvec,
    const int* __restrict__ rowptr, const int* __restrict__ csr_src,
    const int* __restrict__ csr_et, const float* __restrict__ csr_ea,
    const float* __restrict__ bias, float* __restrict__ out,
    unsigned short* __restrict__ A2out) {
  const int wv = threadIdx.x >> 6;
  const int lane = threadIdx.x & 63;
  const int n = blockIdx.x * 4 + wv;
  const int h = lane >> 3;
  const int c0 = lane << 3;  // 8 cols per lane
  const int e0 = rowptr[n], e1 = rowptr[n + 1];
  const float ch = cvec[h];
  const float* qrow = qkbuf + (size_t)n * 128;
  float m = -1e30f, l = 0.f;
  float acc[8] = {};
  // prime pipeline (every node has >=1 edge: self-loop)
  int rN = csr_et[e0];
  float aN = csr_ea[e0];
  int sN = csr_src[e0];
  uint4 tvN = *(const uint4*)&t[((size_t)rN * MPAD + sN) * HD + c0];
  float klogN = qkbuf[(size_t)sN * 128 + rN * 16 + 8 + h];
  for (int e = e0; e < e1; ++e) {
    const int r = rN;
    const float a = aN;
    const uint4 tv = tvN;
    const float klog = klogN;
    const float qv = qrow[r * 16 + h];
    if (e + 1 < e1) {
      const int s2 = csr_src[e + 1];
      rN = csr_et[e + 1];
      aN = csr_ea[e + 1];
      tvN = *(const uint4*)&t[((size_t)rN * MPAD + s2) * HD + c0];
      klogN = qkbuf[(size_t)s2 * 128 + rN * 16 + 8 + h];
    }
    float logit = qv + klog + a * ch;
    logit = (logit > 0.f) ? logit : NEG * logit;
    float p;
    if (logit <= m) {
      p = __expf(logit - m);
    } else {
      const float sc = __expf(m - logit);
      l *= sc;
#pragma unroll
      for (int c = 0; c < 8; ++c) acc[c] *= sc;
      m = logit;
      p = 1.f;
    }
    l += p;
    acc[0] = fmaf(p, __uint_as_float((tv.x & 0xffffu) << 16), acc[0]);
    acc[1] = fmaf(p, __uint_as_float(tv.x & 0xffff0000u), acc[1]);
    acc[2] = fmaf(p, __uint_as_float((tv.y & 0xffffu) << 16), acc[2]);
    acc[3] = fmaf(p, __uint_as_float(tv.y & 0xffff0000u), acc[3]);
    acc[4] = fmaf(p, __uint_as_float((tv.z & 0xffffu) << 16), acc[4]);
    acc[5] = fmaf(p, __uint_as_float(tv.z & 0xffff0000u), acc[5]);
    acc[6] = fmaf(p, __uint_as_float((tv.w & 0xffffu) << 16), acc[6]);
    acc[7] = fmaf(p, __uint_as_float(tv.w & 0xffff0000u), acc[7]);
  }
  const float inv = 1.f / (l + 1e-16f);
  if (CONCAT) {
    unsigned short his[8], los[8];
#pragma unroll
    for (int c = 0; c < 8; ++c) {
      const float vv = fmaf(acc[c], inv, bias[c0 + c]);
      const unsigned short hi = f2bf(vv);
      his[c] = hi;
      los[c] = f2bf(vv - bf2f(hi));
    }
    uint4 wh, wl;
    wh.x = (u32)his[0] | ((u32)his[1] << 16);
    wh.y = (u32)his[2] | ((u32)his[3] << 16);
    wh.z = (u32)his[4] | ((u32)his[5] << 16);
    wh.w = (u32)his[6] | ((u32)his[7] << 16);
    wl.x = (u32)los[0] | ((u32)los[1] << 16);
    wl.y = (u32)los[2] | ((u32)los[3] << 16);
    wl.z = (u32)los[4] | ((u32)los[5] << 16);
    wl.w = (u32)los[6] | ((u32)los[7] << 16);
    *(uint4*)&A2out[(size_t)n * 1024 + c0] = wh;
    *(uint4*)&A2out[(size_t)n * 1024 + 512 + c0] = wl;
  } else {
    __shared__ float sm[4][HD];
#pragma unroll
    for (int c = 0; c < 8; ++c) sm[wv][c0 + c] = acc[c] * inv;
    __syncthreads();
    const int d = lane;
    float s = 0.f;
#pragma unroll
    for (int hh = 0; hh < NHEAD; ++hh) s += sm[wv][hh * 64 + d];
    out[(size_t)n * DOUT + d] = s * 0.125f + bias[d];
  }
}

// ---------- launch ----------
static void run_pipeline(const float* x, const int* ei, const int* et, const float* ea,
                         const float* W1, const float* q1, const float* k1,
                         const float* We1, const float* e1, const float* b1,
                         const float* W2, const float* q2, const float* k2,
                         const float* We2, const float* e2, const float* b2,
                         float* out, float* qkbuf, unsigned short* WQKT,
                         unsigned short* A2, unsigned short* BT,
                         float* cvec, int* meta, int* deg, int* rowptr,
                         int* fill, int* csr_src, int* csr_et, float* csr_ea,
                         unsigned short* t, hipStream_t stream) {
  (void)hipMemsetAsync(meta, 0, 4, stream);
  (void)hipMemsetAsync(deg, 0, (size_t)NN * 4, stream);
  k_hist<<<(ETOT + 255) / 256, 256, 0, stream>>>(ei, et, deg, meta);
  k_scan<<<1, 1024, 0, stream>>>(deg, rowptr, fill);
  k_scatter<<<(ETOT + 255) / 256, 256, 0, stream>>>(ei, et, ea, meta, fill,
                                                    csr_src, csr_et, csr_ea);
  // layer 1 (F=256, Kp=512): A2 row stride 512
  (void)hipMemsetAsync(WQKT, 0, (size_t)256 * 1024 * 2, stream);
  k_wqk<<<RREL * 256 * 16 / 256 + 1, 256, 0, stream>>>(W1, q1, k1, We1, e1, WQKT,
                                                       cvec, 256);
  k_asplit<<<(NN * 64 + 255) / 256, 256, 0, stream>>>(x, A2, 256);
  k_bsplit<<<dim3(4, 8, RREL), 256, 0, stream>>>(W1, BT, 256);
  k_mgemm<<<NMAIN + 63, 512, 0, stream>>>(A2, BT, WQKT, t, qkbuf, 512);
  k_attn<1><<<NN / 4, 256, 0, stream>>>(t, qkbuf, cvec, rowptr, csr_src, csr_et,
                                        csr_ea, b1, nullptr, A2);  // A2 stride 1024
  // layer 2 (F=512, Kp=1024): A2 written by attn<1>
  (void)hipMemsetAsync(WQKT, 0, (size_t)256 * 2048 * 2, stream);
  k_wqk<<<RREL * HD * 16 / 256 + 1, 256, 0, stream>>>(W2, q2, k2, We2, e2, WQKT,
                                                      cvec, HD);
  k_bsplit<<<dim3(8, 8, RREL), 256, 0, stream>>>(W2, BT, HD);
  k_mgemm<<<NMAIN + 63, 512, 0, stream>>>(A2, BT, WQKT, t, qkbuf, 1024);
  k_attn<0><<<NN / 4, 256, 0, stream>>>(t, qkbuf, cvec, rowptr, csr_src, csr_et,
                                        csr_ea, b2, out, nullptr);
}

extern "C" void kernel_launch(void* const* d_in, const int* in_sizes, int n_in,
                              void* d_out, int out_size, void* d_ws, size_t ws_size,
                              hipStream_t stream) {
  const float* x   = (const float*)d_in[0];
  const int*   ei  = (const int*)d_in[1];
  const int*   et  = (const int*)d_in[2];
  const float* ea  = (const float*)d_in[3];
  const float* W1  = (const float*)d_in[4];
  const float* q1  = (const float*)d_in[5];
  const float* k1  = (const float*)d_in[6];
  const float* We1 = (const float*)d_in[7];
  const float* e1  = (const float*)d_in[8];
  const float* b1  = (const float*)d_in[9];
  const float* W2  = (const float*)d_in[10];
  const float* q2  = (const float*)d_in[11];
  const float* k2  = (const float*)d_in[12];
  const float* We2 = (const float*)d_in[13];
  const float* e2  = (const float*)d_in[14];
  const float* b2  = (const float*)d_in[15];
  float* out = (float*)d_out;

  char* w = (char*)d_ws;
  auto alloc = [&](size_t bytes) {
    char* p = w;
    w += (bytes + 255) & ~(size_t)255;
    return p;
  };
  float* qkbuf  = (float*)alloc((size_t)NN * 128 * 4);
  unsigned short* WQKT = (unsigned short*)alloc((size_t)256 * 2048 * 2);
  unsigned short* A2 = (unsigned short*)alloc((size_t)MPAD * 2 * HD * 2);
  unsigned short* BT = (unsigned short*)alloc((size_t)RREL * HD * 2 * HD * 2);
  float* cvec   = (float*)alloc(64);
  int*   meta   = (int*)alloc(64);
  int*   deg    = (int*)alloc((size_t)NN * 4);
  int*   rowptr = (int*)alloc((size_t)(NN + 1) * 4);
  int*   fill   = (int*)alloc((size_t)NN * 4);
  int*   csr_src= (int*)alloc((size_t)ETOT * 4);
  int*   csr_et = (int*)alloc((size_t)ETOT * 4);
  float* csr_ea = (float*)alloc((size_t)ETOT * 4);
  unsigned short* t = (unsigned short*)alloc((size_t)RREL * MPAD * HD * 2);
  (void)ws_size;

  run_pipeline(x, ei, et, ea, W1, q1, k1, We1, e1, b1,
               W2, q2, k2, We2, e2, b2, out, qkbuf, WQKT, A2, BT,
               cvec, meta, deg, rowptr, fill, csr_src, csr_et, csr_ea,
               t, stream);
}

// Round 14
// 476.387 us; speedup vs baseline: 1.4545x; 1.2520x over previous
//
#include <hip/hip_runtime.h>
#include <hip/hip_bf16.h>
#include <cstdint>
#include <cstddef>

#define NN 16000
#define MPAD 16128
#define EE 256000
#define ETOT (EE + NN)
#define RREL 8
#define NHEAD 8
#define DOUT 64
#define HD 512
#define NEG 0.2f
#define NMAIN 1008

typedef unsigned int u32;
typedef short bf16x8 __attribute__((ext_vector_type(8)));
typedef float f32x4 __attribute__((ext_vector_type(4)));

// ---------- helpers ----------
__device__ inline unsigned short f2bf(float f) {
  u32 i = __float_as_uint(f);
  u32 r = (i + 0x7fff + ((i >> 16) & 1)) >> 16;  // RNE, finite values
  return (unsigned short)r;
}
__device__ inline float bf2f(unsigned short h) {
  return __uint_as_float((u32)h << 16);
}
__device__ inline void g2lds16(const void* g, void* lds) {
  __builtin_amdgcn_global_load_lds(
      (const __attribute__((address_space(1))) unsigned int*)g,
      (__attribute__((address_space(3))) unsigned int*)lds, 16, 0, 0);
}

// ---------- preprocessing ----------
__global__ void k_hist(const int* __restrict__ ei, const int* __restrict__ et,
                       int* __restrict__ deg, int* __restrict__ meta) {
  int e = blockIdx.x * 256 + threadIdx.x;
  if (e >= ETOT) return;
  int dst;
  if (e < EE) { dst = ei[EE + e]; atomicMax(&meta[0], et[e]); }
  else dst = e - EE;
  atomicAdd(&deg[dst], 1);
}

// 16 elems/thread serial prefix + single 1024-wide block scan
__global__ __launch_bounds__(1024) void k_scan(const int* __restrict__ deg,
                                               int* __restrict__ rowptr,
                                               int* __restrict__ fill) {
  __shared__ int sm[1024];
  const int tid = threadIdx.x;
  const int base = tid * 16;
  int local[16];
  int s = 0;
#pragma unroll
  for (int i = 0; i < 16; ++i) {
    int idx = base + i;
    int v = (idx < NN) ? deg[idx] : 0;
    local[i] = s;
    s += v;
  }
  sm[tid] = s;
  __syncthreads();
  for (int off = 1; off < 1024; off <<= 1) {
    int t = (tid >= off) ? sm[tid - off] : 0;
    __syncthreads();
    sm[tid] += t;
    __syncthreads();
  }
  const int pre = (tid > 0) ? sm[tid - 1] : 0;
#pragma unroll
  for (int i = 0; i < 16; ++i) {
    int idx = base + i;
    if (idx < NN) { rowptr[idx] = pre + local[i]; fill[idx] = pre + local[i]; }
  }
  if (tid == 1023) rowptr[NN] = sm[1023];
}

__global__ void k_scatter(const int* __restrict__ ei, const int* __restrict__ et,
                          const float* __restrict__ ea, const int* __restrict__ meta,
                          int* __restrict__ fill, int* __restrict__ csr_src,
                          int* __restrict__ csr_et, float* __restrict__ csr_ea) {
  int e = blockIdx.x * 256 + threadIdx.x;
  if (e >= ETOT) return;
  int src, dst, r; float a;
  if (e < EE) { src = ei[e]; dst = ei[EE + e]; r = et[e]; a = ea[e]; }
  else { src = dst = e - EE; r = (meta[0] + 1) & (RREL - 1); a = 0.5f; }
  int pos = atomicAdd(&fill[dst], 1);
  csr_src[pos] = src; csr_et[pos] = r; csr_ea[pos] = a;
}

// ---------- per-layer small precomputes ----------
// WQKT[col][f] bf16-hi; col = r*16+j; extra block -> cvec
__global__ void k_wqk(const float* __restrict__ W, const float* __restrict__ q,
                      const float* __restrict__ k, const float* __restrict__ We,
                      const float* __restrict__ e, unsigned short* __restrict__ WQKT,
                      float* __restrict__ cvec, int F) {
  if ((int)blockIdx.x == (RREL * F * 16) / 256) {
    int j = threadIdx.x;
    if (j < NHEAD) {
      float acc = 0.f;
      for (int h2 = 0; h2 < HD; ++h2) acc += We[h2] * e[h2 * NHEAD + j];
      cvec[j] = acc;
    }
    return;
  }
  int g = blockIdx.x * 256 + threadIdx.x;
  int j = g & 15;
  int rf = g >> 4;  // r*F + f
  int f = rf % F;
  const float* wrow = W + (size_t)rf * HD;
  const float* qk = ((j < 8) ? q : k) + (j & 7);
  float acc = 0.f;
  for (int h = 0; h < HD; ++h) acc += wrow[h] * qk[(size_t)h * NHEAD];
  const int col = (rf / F) * 16 + j;  // 0..127
  WQKT[(size_t)col * F + f] = f2bf(acc);
}

// ---------- bf16-hi operand builders ----------
// in: [NN][F] f32 -> A2: [NN][F] bf16 hi
__global__ void k_asplit(const float* __restrict__ in, unsigned short* __restrict__ A2,
                         int F) {
  long idx = (long)blockIdx.x * 256 + threadIdx.x;  // over NN * F/4
  long total = (long)NN * (F >> 2);
  if (idx >= total) return;
  int row = (int)(idx / (F >> 2));
  int c4 = (int)(idx % (F >> 2)) << 2;
  float4 v = *(const float4*)&in[(size_t)row * F + c4];
  ushort4 hi;
  hi.x = f2bf(v.x); hi.y = f2bf(v.y); hi.z = f2bf(v.z); hi.w = f2bf(v.w);
  *(ushort4*)&A2[(size_t)row * F + c4] = hi;
}

// W: [R][F][512] f32 -> BT: flattened [4096 cols][F] bf16 hi (col-major B)
__global__ __launch_bounds__(256) void k_bsplit(const float* __restrict__ W,
                                                unsigned short* __restrict__ BT, int F) {
  int f0 = blockIdx.x * 64, c0 = blockIdx.y * 64, r = blockIdx.z;
  __shared__ float tile[64][65];
  int tid = threadIdx.x;
  int i0 = tid >> 6;   // 0..3
  int j = tid & 63;
  const float* Wr = W + (size_t)r * F * 512;
  for (int i = i0; i < 64; i += 4)
    tile[i][j] = Wr[(size_t)(f0 + i) * 512 + c0 + j];
  __syncthreads();
  unsigned short* Br = BT + (size_t)r * 512 * F;
  for (int c = i0; c < 64; c += 4) {
    float v = tile[j][c];  // W[r][f0+j][c0+c]
    Br[(size_t)(c0 + c) * F + f0 + j] = f2bf(v);
  }
}

// ---------- MFMA GEMM (round-9 structure) + fused qk blocks ----------
// bid < NMAIN: C = A2[16128 x Kp] @ BT^T (N=4096), bf16 t output.
// bid >= NMAIN: 63 blocks computing qkbuf = A2 @ WQKT^T (cols<128, f32).
// BM=BN=256, BK=32, 8 waves (2M x 4N), 3 LDS buffers (96 KB), prefetch
// distance 2, counted vmcnt(4). Fragment-ordered LDS -> conflict-free.
__global__ __launch_bounds__(512, 2) void k_mgemm(const unsigned short* __restrict__ A2,
                                                  const unsigned short* __restrict__ BT,
                                                  const unsigned short* __restrict__ WQKT,
                                                  unsigned short* __restrict__ Ct,
                                                  float* __restrict__ qkbuf,
                                                  int Kp) {
  const int bid = blockIdx.x;
  const bool isqk = (bid >= NMAIN);
  int m0, n0;
  const unsigned short* Bbase;
  if (!isqk) {
    const int v = (bid & 7) * 126 + (bid >> 3);   // 1008 = 8*126, bijective
    m0 = (v >> 4) << 8;
    n0 = (v & 15) << 8;
    Bbase = BT;
  } else {
    m0 = (bid - NMAIN) << 8;
    n0 = 0;
    Bbase = WQKT;
  }

  __shared__ __align__(16) unsigned short smem[49152];  // 96 KB

  const int tid = threadIdx.x;
  const int wid = tid >> 6;
  const int lane = tid & 63;
  const int wr = wid >> 2;     // 0..1 (m half)
  const int wc = wid & 3;      // 0..3 (n quarter)
  const int rlow = lane & 15;
  const int kch = lane >> 4;   // 0..3

  const unsigned short* srcA[2];
  const unsigned short* srcB[2];
  int dstOff[2];
#pragma unroll
  for (int p = 0; p < 2; ++p) {
    int fr = (p << 3) + wid;   // 0..15
    srcA[p] = A2 + (size_t)(m0 + fr * 16 + rlow) * Kp + kch * 8;
    srcB[p] = Bbase + (size_t)(n0 + fr * 16 + rlow) * Kp + kch * 8;
    dstOff[p] = fr * 512;
  }

  f32x4 acc[8][4] = {};
  const int nt = Kp >> 5;

  // prologue: stage tiles 0,1 into buffers 0,1
#pragma unroll
  for (int tp = 0; tp < 2; ++tp) {
    const int ko = tp << 5;
#pragma unroll
    for (int p = 0; p < 2; ++p) {
      g2lds16(srcA[p] + ko, &smem[tp * 8192 + dstOff[p]]);
      g2lds16(srcB[p] + ko, &smem[24576 + tp * 8192 + dstOff[p]]);
    }
  }

  int buf = 0;
  for (int u = 0; u < nt; ++u) {
    if (u + 1 < nt)
      asm volatile("s_waitcnt vmcnt(4)" ::: "memory");
    else
      asm volatile("s_waitcnt vmcnt(0)" ::: "memory");
    __builtin_amdgcn_s_barrier();
    asm volatile("" ::: "memory");
    if (u + 2 < nt) {
      int nb2 = buf + 2; if (nb2 >= 3) nb2 -= 3;
      const int ko = (u + 2) << 5;
#pragma unroll
      for (int p = 0; p < 2; ++p) {
        g2lds16(srcA[p] + ko, &smem[nb2 * 8192 + dstOff[p]]);
        g2lds16(srcB[p] + ko, &smem[24576 + nb2 * 8192 + dstOff[p]]);
      }
    }
    const unsigned short* Ab = smem + buf * 8192;
    const unsigned short* Bb = smem + 24576 + buf * 8192;
    bf16x8 af[8], bv[4];
#pragma unroll
    for (int i = 0; i < 8; ++i)
      af[i] = *(const bf16x8*)&Ab[(wr * 8 + i) * 512 + lane * 8];
#pragma unroll
    for (int j = 0; j < 4; ++j)
      bv[j] = *(const bf16x8*)&Bb[(wc * 4 + j) * 512 + lane * 8];
    __builtin_amdgcn_s_setprio(1);
#pragma unroll
    for (int i = 0; i < 8; ++i)
#pragma unroll
      for (int j = 0; j < 4; ++j)
        acc[i][j] = __builtin_amdgcn_mfma_f32_16x16x32_bf16(af[i], bv[j],
                                                            acc[i][j], 0, 0, 0);
    __builtin_amdgcn_s_setprio(0);
    buf = (buf == 2) ? 0 : buf + 1;
  }

  if (!isqk) {
    // ---- epilogue: per-wave private LDS transpose, bf16 t output ----
    __syncthreads();
    float* epsW = (float*)smem + wid * 1344;  // 64 cols x 21 pad
    const int rowL = lane & 15;
    const int cseg = lane >> 4;
    const int colfull0 = n0 + wc * 64;
    const int rr = colfull0 >> 9;
    const int hbase = (colfull0 & 511) + cseg * 16;
#pragma unroll
    for (int i = 0; i < 8; ++i) {
#pragma unroll
      for (int j = 0; j < 4; ++j)
        *(f32x4*)&epsW[(j * 16 + rlow) * 21 + kch * 4] = acc[i][j];
      float vals[16];
#pragma unroll
      for (int c = 0; c < 16; ++c) vals[c] = epsW[(cseg * 16 + c) * 21 + rowL];
      const int rowg = m0 + wr * 128 + i * 16 + rowL;
      unsigned short* dst = Ct + ((size_t)rr * MPAD + rowg) * HD + hbase;
      uint4 w0, w1;
      w0.x = (u32)f2bf(vals[0])  | ((u32)f2bf(vals[1])  << 16);
      w0.y = (u32)f2bf(vals[2])  | ((u32)f2bf(vals[3])  << 16);
      w0.z = (u32)f2bf(vals[4])  | ((u32)f2bf(vals[5])  << 16);
      w0.w = (u32)f2bf(vals[6])  | ((u32)f2bf(vals[7])  << 16);
      w1.x = (u32)f2bf(vals[8])  | ((u32)f2bf(vals[9])  << 16);
      w1.y = (u32)f2bf(vals[10]) | ((u32)f2bf(vals[11]) << 16);
      w1.z = (u32)f2bf(vals[12]) | ((u32)f2bf(vals[13]) << 16);
      w1.w = (u32)f2bf(vals[14]) | ((u32)f2bf(vals[15]) << 16);
      *(uint4*)dst = w0;
      *(uint4*)(dst + 8) = w1;
    }
  } else {
    // ---- qk epilogue: direct f32 stores for cols < 128 ----
    if (wc < 2) {
#pragma unroll
      for (int i = 0; i < 8; ++i) {
        const int row0 = m0 + wr * 128 + i * 16 + kch * 4;
#pragma unroll
        for (int j = 0; j < 4; ++j) {
          const int col = wc * 64 + j * 16 + rlow;
#pragma unroll
          for (int q = 0; q < 4; ++q) {
            const int row = row0 + q;
            if (row < NN) qkbuf[(size_t)row * 128 + col] = acc[i][j][q];
          }
        }
      }
    }
  }
}

// ---------- fused attention: one WAVE per dst node, online rescale-skip ---
// 2-deep software pipeline. CONCAT=1 emits bf16-hi h directly into A2.
template <int CONCAT>
__global__ __launch_bounds__(256) void k_attn(const unsigned short* __restrict__ t,
    const float* __restrict__ qkbuf, const float* __restrict__ cvec,
    const int* __restrict__ rowptr, const int* __restrict__ csr_src,
    const int* __restrict__ csr_et, const float* __restrict__ csr_ea,
    const float* __restrict__ bias, float* __restrict__ out,
    unsigned short* __restrict__ A2out) {
  const int wv = threadIdx.x >> 6;
  const int lane = threadIdx.x & 63;
  const int n = blockIdx.x * 4 + wv;
  const int h = lane >> 3;
  const int c0 = lane << 3;  // 8 cols per lane
  const int e0 = rowptr[n], e1 = rowptr[n + 1];
  const float ch = cvec[h];
  const float* qrow = qkbuf + (size_t)n * 128;
  float m = -1e30f, l = 0.f;
  float acc[8] = {};
  // prime pipeline (every node has >=1 edge: self-loop)
  int rN = csr_et[e0];
  float aN = csr_ea[e0];
  int sN = csr_src[e0];
  uint4 tvN = *(const uint4*)&t[((size_t)rN * MPAD + sN) * HD + c0];
  float klogN = qkbuf[(size_t)sN * 128 + rN * 16 + 8 + h];
  for (int e = e0; e < e1; ++e) {
    const int r = rN;
    const float a = aN;
    const uint4 tv = tvN;
    const float klog = klogN;
    const float qv = qrow[r * 16 + h];
    if (e + 1 < e1) {
      const int s2 = csr_src[e + 1];
      rN = csr_et[e + 1];
      aN = csr_ea[e + 1];
      tvN = *(const uint4*)&t[((size_t)rN * MPAD + s2) * HD + c0];
      klogN = qkbuf[(size_t)s2 * 128 + rN * 16 + 8 + h];
    }
    float logit = qv + klog + a * ch;
    logit = (logit > 0.f) ? logit : NEG * logit;
    float p;
    if (logit <= m) {
      p = __expf(logit - m);
    } else {
      const float sc = __expf(m - logit);
      l *= sc;
#pragma unroll
      for (int c = 0; c < 8; ++c) acc[c] *= sc;
      m = logit;
      p = 1.f;
    }
    l += p;
    acc[0] = fmaf(p, __uint_as_float((tv.x & 0xffffu) << 16), acc[0]);
    acc[1] = fmaf(p, __uint_as_float(tv.x & 0xffff0000u), acc[1]);
    acc[2] = fmaf(p, __uint_as_float((tv.y & 0xffffu) << 16), acc[2]);
    acc[3] = fmaf(p, __uint_as_float(tv.y & 0xffff0000u), acc[3]);
    acc[4] = fmaf(p, __uint_as_float((tv.z & 0xffffu) << 16), acc[4]);
    acc[5] = fmaf(p, __uint_as_float(tv.z & 0xffff0000u), acc[5]);
    acc[6] = fmaf(p, __uint_as_float((tv.w & 0xffffu) << 16), acc[6]);
    acc[7] = fmaf(p, __uint_as_float(tv.w & 0xffff0000u), acc[7]);
  }
  const float inv = 1.f / (l + 1e-16f);
  if (CONCAT) {
    unsigned short his[8];
#pragma unroll
    for (int c = 0; c < 8; ++c)
      his[c] = f2bf(fmaf(acc[c], inv, bias[c0 + c]));
    uint4 wh;
    wh.x = (u32)his[0] | ((u32)his[1] << 16);
    wh.y = (u32)his[2] | ((u32)his[3] << 16);
    wh.z = (u32)his[4] | ((u32)his[5] << 16);
    wh.w = (u32)his[6] | ((u32)his[7] << 16);
    *(uint4*)&A2out[(size_t)n * 512 + c0] = wh;
  } else {
    __shared__ float sm[4][HD];
#pragma unroll
    for (int c = 0; c < 8; ++c) sm[wv][c0 + c] = acc[c] * inv;
    __syncthreads();
    const int d = lane;
    float s = 0.f;
#pragma unroll
    for (int hh = 0; hh < NHEAD; ++hh) s += sm[wv][hh * 64 + d];
    out[(size_t)n * DOUT + d] = s * 0.125f + bias[d];
  }
}

// ---------- launch ----------
static void run_pipeline(const float* x, const int* ei, const int* et, const float* ea,
                         const float* W1, const float* q1, const float* k1,
                         const float* We1, const float* e1, const float* b1,
                         const float* W2, const float* q2, const float* k2,
                         const float* We2, const float* e2, const float* b2,
                         float* out, float* qkbuf, unsigned short* WQKT,
                         unsigned short* A2, unsigned short* BT,
                         float* cvec, int* meta, int* deg, int* rowptr,
                         int* fill, int* csr_src, int* csr_et, float* csr_ea,
                         unsigned short* t, hipStream_t stream) {
  (void)hipMemsetAsync(meta, 0, 4, stream);
  (void)hipMemsetAsync(deg, 0, (size_t)NN * 4, stream);
  k_hist<<<(ETOT + 255) / 256, 256, 0, stream>>>(ei, et, deg, meta);
  k_scan<<<1, 1024, 0, stream>>>(deg, rowptr, fill);
  k_scatter<<<(ETOT + 255) / 256, 256, 0, stream>>>(ei, et, ea, meta, fill,
                                                    csr_src, csr_et, csr_ea);
  // layer 1 (F=256 -> Kp=256): A2 row stride 256
  k_wqk<<<RREL * 256 * 16 / 256 + 1, 256, 0, stream>>>(W1, q1, k1, We1, e1, WQKT,
                                                       cvec, 256);
  k_asplit<<<(NN * 64 + 255) / 256, 256, 0, stream>>>(x, A2, 256);
  k_bsplit<<<dim3(4, 8, RREL), 256, 0, stream>>>(W1, BT, 256);
  k_mgemm<<<NMAIN + 63, 512, 0, stream>>>(A2, BT, WQKT, t, qkbuf, 256);
  k_attn<1><<<NN / 4, 256, 0, stream>>>(t, qkbuf, cvec, rowptr, csr_src, csr_et,
                                        csr_ea, b1, nullptr, A2);  // A2 stride 512
  // layer 2 (F=512 -> Kp=512): A2 written by attn<1>
  k_wqk<<<RREL * HD * 16 / 256 + 1, 256, 0, stream>>>(W2, q2, k2, We2, e2, WQKT,
                                                      cvec, HD);
  k_bsplit<<<dim3(8, 8, RREL), 256, 0, stream>>>(W2, BT, HD);
  k_mgemm<<<NMAIN + 63, 512, 0, stream>>>(A2, BT, WQKT, t, qkbuf, 512);
  k_attn<0><<<NN / 4, 256, 0, stream>>>(t, qkbuf, cvec, rowptr, csr_src, csr_et,
                                        csr_ea, b2, out, nullptr);
}

extern "C" void kernel_launch(void* const* d_in, const int* in_sizes, int n_in,
                              void* d_out, int out_size, void* d_ws, size_t ws_size,
                              hipStream_t stream) {
  const float* x   = (const float*)d_in[0];
  const int*   ei  = (const int*)d_in[1];
  const int*   et  = (const int*)d_in[2];
  const float* ea  = (const float*)d_in[3];
  const float* W1  = (const float*)d_in[4];
  const float* q1  = (const float*)d_in[5];
  const float* k1  = (const float*)d_in[6];
  const float* We1 = (const float*)d_in[7];
  const float* e1  = (const float*)d_in[8];
  const float* b1  = (const float*)d_in[9];
  const float* W2  = (const float*)d_in[10];
  const float* q2  = (const float*)d_in[11];
  const float* k2  = (const float*)d_in[12];
  const float* We2 = (const float*)d_in[13];
  const float* e2  = (const float*)d_in[14];
  const float* b2  = (const float*)d_in[15];
  float* out = (float*)d_out;

  char* w = (char*)d_ws;
  auto alloc = [&](size_t bytes) {
    char* p = w;
    w += (bytes + 255) & ~(size_t)255;
    return p;
  };
  float* qkbuf  = (float*)alloc((size_t)NN * 128 * 4);
  unsigned short* WQKT = (unsigned short*)alloc((size_t)256 * HD * 2);
  unsigned short* A2 = (unsigned short*)alloc((size_t)MPAD * HD * 2);
  unsigned short* BT = (unsigned short*)alloc((size_t)RREL * HD * HD * 2);
  float* cvec   = (float*)alloc(64);
  int*   meta   = (int*)alloc(64);
  int*   deg    = (int*)alloc((size_t)NN * 4);
  int*   rowptr = (int*)alloc((size_t)(NN + 1) * 4);
  int*   fill   = (int*)alloc((size_t)NN * 4);
  int*   csr_src= (int*)alloc((size_t)ETOT * 4);
  int*   csr_et = (int*)alloc((size_t)ETOT * 4);
  float* csr_ea = (float*)alloc((size_t)ETOT * 4);
  unsigned short* t = (unsigned short*)alloc((size_t)RREL * MPAD * HD * 2);
  (void)ws_size;

  run_pipeline(x, ei, et, ea, W1, q1, k1, We1, e1, b1,
               W2, q2, k2, We2, e2, b2, out, qkbuf, WQKT, A2, BT,
               cvec, meta, deg, rowptr, fill, csr_src, csr_et, csr_ea,
               t, stream);
}